// Round 1
// baseline (954.277 us; speedup 1.0000x reference)
//
#include <hip/hip_runtime.h>
#include <cfloat>

// Problem constants (from reference): L=6, N=16384, C=8, F=128, H=128
#define LL 6
#define NN 16384
#define CC 8
#define FF 128
#define HH 128
#define TN 8   // nodes per block

// ---------------------------------------------------------------------------
// child_mask dtype detection: the harness passes bool either as 1-byte or
// int32. For int32 0/1 little-endian values, every byte at offset %4 != 0 is
// zero; for random 0/1 bytes that is impossible. Scan a prefix (always
// in-bounds under both layouts since we only touch < L*N*C bytes).
// flag = 1 -> int32 layout, flag = 0 -> byte layout.
// ---------------------------------------------------------------------------
__global__ void detect_mask_kernel(const unsigned char* __restrict__ raw,
                                   int* __restrict__ flag) {
    __shared__ int any;
    if (threadIdx.x == 0) any = 0;
    __syncthreads();
    int local = 0;
    const int scan = 65536;  // < L*N*C = 786432 bytes, safe either way
    for (int i = threadIdx.x; i < scan; i += blockDim.x) {
        if ((i & 3) != 0 && raw[i] != 0) local = 1;
    }
    if (local) atomicOr(&any, 1);
    __syncthreads();
    if (threadIdx.x == 0) *flag = any ? 0 : 1;
}

// Canonicalize mask to u8. Index computed arithmetically so the single load
// is always within the true buffer extent for the detected layout.
__global__ void convert_mask_kernel(const unsigned char* __restrict__ raw,
                                    const int* __restrict__ flag,
                                    unsigned char* __restrict__ mask_u8) {
    const int i = blockIdx.x * blockDim.x + threadIdx.x;
    if (i >= LL * NN * CC) return;
    const int f = *flag;                 // 1 -> int32 layout (read low byte)
    const int idx = f ? (i << 2) : i;
    mask_u8[i] = (raw[idx] != 0) ? 1 : 0;
}

// ---------------------------------------------------------------------------
// One level:
//   ch[n][c]   = mask[n][c] ? h_prev[cidx[n][c]] : 0          (gather)
//   t[n][c]    = sum_d a[n][c][d] * ch[n][d]                  (8x8 mix)
//   g[n][c][h] = relu( sum_d t[n][c][d] * Wg[d][h] )          (GEMM-ish)
//   pooled     = masked max_c g, 0 if no children
//   h_new      = tanh( x@Wih + pooled@Whh + bih + bhh )
// Block: 256 threads = (h in [0,128)) x (sub in {0,1}); sub owns 4 nodes.
// ---------------------------------------------------------------------------
__global__ __launch_bounds__(256) void level_kernel(
    const float* __restrict__ x_l,            // [N][F]
    const int* __restrict__ cidx_l,           // [N][C]
    const unsigned char* __restrict__ mask_l, // [N][C]
    const float* __restrict__ a_l,            // [N][C][C]
    const float* __restrict__ Wg,             // [H][H]  (d-major)
    const float* __restrict__ Wih,            // [F][H]
    const float* __restrict__ Whh,            // [H][H]
    const float* __restrict__ bih,            // [H]
    const float* __restrict__ bhh,            // [H]
    const float* __restrict__ h_prev,         // [N][H]
    float* __restrict__ h_out)                // [N][H]
{
    __shared__ float t_lds[TN * CC][HH];      // 32 KB
    __shared__ float a_lds[TN][CC][CC];       // 2 KB
    __shared__ float x_lds[TN][FF];           // 4 KB
    __shared__ float pooled_lds[TN][HH];      // 4 KB
    __shared__ int   cidx_lds[TN][CC];
    __shared__ unsigned char mask_lds[TN][CC];

    const int tid  = threadIdx.x;
    const int h    = tid & (HH - 1);
    const int sub  = tid >> 7;                 // 0..1
    const long nbase = (long)blockIdx.x * TN;

    // --- stage per-node small data ---
    for (int i = tid; i < TN * CC * CC; i += 256)
        ((float*)a_lds)[i] = a_l[nbase * CC * CC + i];
    if (tid < TN * CC) {
        cidx_lds[tid >> 3][tid & 7] = cidx_l[nbase * CC + tid];
        mask_lds[tid >> 3][tid & 7] = mask_l[nbase * CC + tid];
    }
    for (int i = tid; i < TN * FF; i += 256)
        ((float*)x_lds)[i] = x_l[nbase * FF + i];
    __syncthreads();

    // --- Phase A: gather children + 8x8 mix -> t_lds ---
    #pragma unroll
    for (int nl = 0; nl < TN / 2; ++nl) {
        const int node = sub * (TN / 2) + nl;
        float ch[CC];
        #pragma unroll
        for (int c = 0; c < CC; ++c) {
            float v = 0.0f;
            if (mask_lds[node][c])
                v = h_prev[(long)cidx_lds[node][c] * HH + h];
            ch[c] = v;
        }
        #pragma unroll
        for (int c = 0; c < CC; ++c) {
            float acc = 0.0f;
            #pragma unroll
            for (int d = 0; d < CC; ++d) acc += a_lds[node][c][d] * ch[d];
            t_lds[node * CC + c][h] = acc;
        }
    }
    __syncthreads();

    // --- Phase B: g = relu(t @ Wg), thread owns column h for 4 nodes x 8 c ---
    float acc[TN / 2][CC];
    #pragma unroll
    for (int nl = 0; nl < TN / 2; ++nl)
        #pragma unroll
        for (int c = 0; c < CC; ++c) acc[nl][c] = 0.0f;

    for (int d0 = 0; d0 < HH; d0 += 4) {
        const float w0 = Wg[(d0 + 0) * HH + h];
        const float w1 = Wg[(d0 + 1) * HH + h];
        const float w2 = Wg[(d0 + 2) * HH + h];
        const float w3 = Wg[(d0 + 3) * HH + h];
        #pragma unroll
        for (int nl = 0; nl < TN / 2; ++nl) {
            const int node = sub * (TN / 2) + nl;
            #pragma unroll
            for (int c = 0; c < CC; ++c) {
                const float4 t4 = *(const float4*)&t_lds[node * CC + c][d0];
                acc[nl][c] += t4.x * w0 + t4.y * w1 + t4.z * w2 + t4.w * w3;
            }
        }
    }

    // --- Phase C: masked max-pool over children ---
    #pragma unroll
    for (int nl = 0; nl < TN / 2; ++nl) {
        const int node = sub * (TN / 2) + nl;
        float m = -FLT_MAX;
        int any = 0;
        #pragma unroll
        for (int c = 0; c < CC; ++c) {
            if (mask_lds[node][c]) {
                any = 1;
                m = fmaxf(m, fmaxf(acc[nl][c], 0.0f));
            }
        }
        pooled_lds[node][h] = any ? m : 0.0f;
    }
    __syncthreads();

    // --- Phase D: h_new = tanh(x@Wih + pooled@Whh + b) ---
    float acc2[TN / 2] = {0.0f, 0.0f, 0.0f, 0.0f};
    for (int d0 = 0; d0 < HH; d0 += 4) {
        const float wi0 = Wih[(d0 + 0) * HH + h];
        const float wi1 = Wih[(d0 + 1) * HH + h];
        const float wi2 = Wih[(d0 + 2) * HH + h];
        const float wi3 = Wih[(d0 + 3) * HH + h];
        const float wh0 = Whh[(d0 + 0) * HH + h];
        const float wh1 = Whh[(d0 + 1) * HH + h];
        const float wh2 = Whh[(d0 + 2) * HH + h];
        const float wh3 = Whh[(d0 + 3) * HH + h];
        #pragma unroll
        for (int nl = 0; nl < TN / 2; ++nl) {
            const int node = sub * (TN / 2) + nl;
            const float4 xv = *(const float4*)&x_lds[node][d0];
            const float4 pv = *(const float4*)&pooled_lds[node][d0];
            acc2[nl] += xv.x * wi0 + xv.y * wi1 + xv.z * wi2 + xv.w * wi3
                      + pv.x * wh0 + pv.y * wh1 + pv.z * wh2 + pv.w * wh3;
        }
    }
    const float bias = bih[h] + bhh[h];
    #pragma unroll
    for (int nl = 0; nl < TN / 2; ++nl) {
        const int node = sub * (TN / 2) + nl;
        h_out[(nbase + node) * HH + h] = tanhf(acc2[nl] + bias);
    }
}

extern "C" void kernel_launch(void* const* d_in, const int* in_sizes, int n_in,
                              void* d_out, int out_size, void* d_ws, size_t ws_size,
                              hipStream_t stream) {
    const float* node_features = (const float*)d_in[0];
    const int*   child_idx     = (const int*)d_in[1];
    const unsigned char* child_mask_raw = (const unsigned char*)d_in[2];
    const float* A_c  = (const float*)d_in[3];
    const float* Wg   = (const float*)d_in[4];
    const float* Wih  = (const float*)d_in[5];
    const float* Whh  = (const float*)d_in[6];
    const float* bih  = (const float*)d_in[7];
    const float* bhh  = (const float*)d_in[8];
    float* out = (float*)d_out;

    char* ws = (char*)d_ws;
    int* flag = (int*)ws;                                    // 4 B
    unsigned char* mask_u8 = (unsigned char*)(ws + 256);     // L*N*C bytes
    float* hbuf = (float*)(ws + (1 << 20));                  // N*H floats

    detect_mask_kernel<<<1, 256, 0, stream>>>(child_mask_raw, flag);
    convert_mask_kernel<<<(LL * NN * CC + 255) / 256, 256, 0, stream>>>(
        child_mask_raw, flag, mask_u8);

    // Process levels in reversed order (level L-1 first). Level L-1 has all
    // masks false -> h_prev never read -> no h0 initialization needed.
    // Ping-pong: odd steps (incl. final step s=5) write d_out, even steps ws.
    const float* hp = hbuf;  // never actually read on step 0
    for (int s = 0; s < LL; ++s) {
        const int l = LL - 1 - s;
        float* ho = (s & 1) ? out : hbuf;
        level_kernel<<<NN / TN, 256, 0, stream>>>(
            node_features + (size_t)l * NN * FF,
            child_idx     + (size_t)l * NN * CC,
            mask_u8       + (size_t)l * NN * CC,
            A_c           + (size_t)l * NN * CC * CC,
            Wg, Wih, Whh, bih, bhh,
            hp, ho);
        hp = ho;
    }
}

// Round 3
// 320.885 us; speedup vs baseline: 2.9739x; 2.9739x over previous
//
#include <hip/hip_runtime.h>
#include <cfloat>

// Problem constants: L=6, N=16384, C=8, F=128, H=128
#define LL 6
#define NN 16384
#define CC 8
#define FF 128
#define HH 128
#define BN 16   // nodes per block

typedef __bf16 bf16x8 __attribute__((ext_vector_type(8)));
typedef __attribute__((ext_vector_type(4))) float f32x4;

static __device__ inline unsigned short f2bfbits(float f) {
    return __builtin_bit_cast(unsigned short, (__bf16)f);
}
static __device__ inline float bfbits2f(unsigned short b) {
    return (float)__builtin_bit_cast(__bf16, b);
}

// ---------------------------------------------------------------------------
// child_mask dtype detection (bool may arrive as u8 or int32). For int32 0/1
// LE values every byte at offset %4!=0 is zero. Scan an always-in-bounds
// prefix. flag=1 -> int32 layout.
// ---------------------------------------------------------------------------
__global__ void detect_mask_kernel(const unsigned char* __restrict__ raw,
                                   int* __restrict__ flag) {
    __shared__ int any;
    if (threadIdx.x == 0) any = 0;
    __syncthreads();
    int local = 0;
    const int scan = 65536;  // < L*N*C bytes, safe either way
    for (int i = threadIdx.x; i < scan; i += blockDim.x) {
        if ((i & 3) != 0 && raw[i] != 0) local = 1;
    }
    if (local) atomicOr(&any, 1);
    __syncthreads();
    if (threadIdx.x == 0) *flag = any ? 0 : 1;
}

__global__ void convert_mask_kernel(const unsigned char* __restrict__ raw,
                                    const int* __restrict__ flag,
                                    unsigned char* __restrict__ mask_u8) {
    const int i = blockIdx.x * blockDim.x + threadIdx.x;
    if (i >= LL * NN * CC) return;
    const int f = *flag;
    const int idx = f ? (i << 2) : i;
    mask_u8[i] = (raw[idx] != 0) ? 1 : 0;
}

// ---------------------------------------------------------------------------
// One-time weight packing into MFMA B-fragment order, split hi/lo bf16.
// B-frag (16x16x32): lane l supplies B[k][n], n = l&15, k = 8*(l>>4)+i.
// WgHi/WgLo : [nt(8)][kt(4)][lane(64)][i(8)] of Wg
// WdHi/WdLo : [nt(8)][kt(8)][lane(64)][i(8)] of [Wih;Whh]
// bias: bih+bhh
// ---------------------------------------------------------------------------
__global__ void pack_weights_kernel(const float* __restrict__ Wg,
                                    const float* __restrict__ Wih,
                                    const float* __restrict__ Whh,
                                    const float* __restrict__ bih,
                                    const float* __restrict__ bhh,
                                    unsigned short* __restrict__ WgHi,
                                    unsigned short* __restrict__ WgLo,
                                    unsigned short* __restrict__ WdHi,
                                    unsigned short* __restrict__ WdLo,
                                    float* __restrict__ bias) {
    const int t = blockIdx.x * 256 + threadIdx.x;
    if (t < 2048) {                      // Wg: (nt*4+kt)*64+lane == t
        const int l = t & 63;
        const int nt = t >> 8;
        const int kt = (t >> 6) & 3;
        const int n = nt * 16 + (l & 15);
        const int kb = kt * 32 + (l >> 4) * 8;
        #pragma unroll
        for (int i = 0; i < 8; ++i) {
            const float v = Wg[(kb + i) * HH + n];
            const unsigned short hb = f2bfbits(v);
            WgHi[t * 8 + i] = hb;
            WgLo[t * 8 + i] = f2bfbits(v - bfbits2f(hb));
        }
    } else if (t < 6144) {               // Wd: u = (nt*8+kt)*64+lane
        const int u = t - 2048;
        const int l = u & 63;
        const int nt = u >> 9;
        const int kt = (u >> 6) & 7;
        const int n = nt * 16 + (l & 15);
        const int kb = (kt & 3) * 32 + (l >> 4) * 8;
        const float* W = (kt < 4) ? Wih : Whh;
        #pragma unroll
        for (int i = 0; i < 8; ++i) {
            const float v = W[(kb + i) * HH + n];
            const unsigned short hb = f2bfbits(v);
            WdHi[u * 8 + i] = hb;
            WdLo[u * 8 + i] = f2bfbits(v - bfbits2f(hb));
        }
    } else if (t < 6272) {
        const int n = t - 6144;
        bias[n] = bih[n] + bhh[n];
    }
}

// byte-offset swizzle for 256B-stride rows (breaks 16-way bank conflict)
#define SWZ(row, byte) ((unsigned)(((row) * 256 + (byte)) ^ (((row) & 7) << 4)))

// ---------------------------------------------------------------------------
// One level, fused: gather+mix (fp32 VALU) -> t split-bf16 in LDS ->
// GEMM-B MFMA split-bf16 (t@Wg, relu+masked maxpool in-register) ->
// pooled split-bf16 in LDS -> GEMM-D MFMA split-bf16 ([x|pooled]@[Wih;Whh])
// -> tanh -> h_out. Block: 256 threads = 4 waves; BN=16 nodes.
// ---------------------------------------------------------------------------
__global__ __launch_bounds__(256) void level_kernel(
    const float* __restrict__ x_l,            // [N][F]
    const int* __restrict__ cidx_l,           // [N][C]
    const unsigned char* __restrict__ mask_l, // [N][C]
    const float* __restrict__ a_l,            // [N][C][C]
    const unsigned short* __restrict__ WgHi,
    const unsigned short* __restrict__ WgLo,
    const unsigned short* __restrict__ WdHi,
    const unsigned short* __restrict__ WdLo,
    const float* __restrict__ bias,
    const float* __restrict__ h_prev,         // [N][H]
    float* __restrict__ h_out)                // [N][H]
{
    __shared__ __align__(16) unsigned char tH_raw[BN * CC * 256];  // 32 KB t hi
    __shared__ __align__(16) unsigned char tL_raw[BN * CC * 256];  // 32 KB t lo
    __shared__ __align__(16) unsigned char pH[BN * 256];           // 4 KB pooled hi
    __shared__ __align__(16) unsigned char pL[BN * 256];           // 4 KB pooled lo
    __shared__ float a_lds[BN][CC][CC];
    __shared__ int   cidx_lds[BN][CC];
    __shared__ unsigned char mask_lds[BN][CC];
    __shared__ unsigned char anyc_lds[BN];

    const int tid = threadIdx.x;
    const int lane = tid & 63;
    const int w = tid >> 6;
    const long nbase = (long)blockIdx.x * BN;

    // --- stage per-node small data ---
    for (int i = tid; i < BN * CC * CC; i += 256)
        ((float*)a_lds)[i] = a_l[nbase * CC * CC + i];
    if (tid < BN * CC) {
        cidx_lds[tid >> 3][tid & 7] = cidx_l[nbase * CC + tid];
        mask_lds[tid >> 3][tid & 7] = mask_l[nbase * CC + tid];
    }
    __syncthreads();
    if (tid < BN) {
        unsigned char any = 0;
        #pragma unroll
        for (int c = 0; c < CC; ++c) any |= mask_lds[tid][c];
        anyc_lds[tid] = any;
    }

    // --- Phase A: gather + 8x8 mix (fp32), write t as split-bf16 pairs ---
    // wave w owns nodes w*4..w*4+3; lane owns column pair (2*lane, 2*lane+1)
    const int h2 = lane;
    for (int nl = 0; nl < 4; ++nl) {
        const int node = w * 4 + nl;
        float c0[CC], c1[CC];
        #pragma unroll
        for (int c = 0; c < CC; ++c) {
            float a0 = 0.f, a1 = 0.f;
            if (mask_lds[node][c]) {  // wave-uniform branch: skipped loads free
                const float2 v = *(const float2*)&h_prev[(long)cidx_lds[node][c] * HH + 2 * h2];
                a0 = v.x; a1 = v.y;
            }
            c0[c] = a0; c1[c] = a1;
        }
        #pragma unroll
        for (int c = 0; c < CC; ++c) {
            float s0 = 0.f, s1 = 0.f;
            #pragma unroll
            for (int d = 0; d < CC; ++d) {
                const float av = a_lds[node][c][d];
                s0 += av * c0[d]; s1 += av * c1[d];
            }
            const int row = node * CC + c;
            const unsigned short h0 = f2bfbits(s0);
            const unsigned short h1 = f2bfbits(s1);
            const unsigned short l0 = f2bfbits(s0 - bfbits2f(h0));
            const unsigned short l1 = f2bfbits(s1 - bfbits2f(h1));
            const unsigned off = SWZ(row, h2 * 4);
            *(unsigned*)&tH_raw[off] = (unsigned)h0 | ((unsigned)h1 << 16);
            *(unsigned*)&tL_raw[off] = (unsigned)l0 | ((unsigned)l1 << 16);
        }
    }
    __syncthreads();

    // --- GEMM-B: g = relu(t @ Wg) split-bf16 + masked maxpool ---
    const int lrow = lane & 15, lgrp = lane >> 4;
    bf16x8 afrH[2][4], afrL[2][4];
    #pragma unroll
    for (int mt = 0; mt < 2; ++mt) {
        const int mtg = w * 2 + mt;
        #pragma unroll
        for (int kt = 0; kt < 4; ++kt) {
            const int row = mtg * 16 + lrow;
            const unsigned off = SWZ(row, kt * 64 + lgrp * 16);
            afrH[mt][kt] = *(const bf16x8*)&tH_raw[off];
            afrL[mt][kt] = *(const bf16x8*)&tL_raw[off];
        }
    }
    // per-lane mask bits: D row = lgrp*4+reg -> node_loc=lgrp>>1, c=(lgrp&1)*4+reg
    const int c_of = (lgrp & 1) * 4;
    int mask4[2];
    #pragma unroll
    for (int mt = 0; mt < 2; ++mt) {
        const int node = (w * 2 + mt) * 2 + (lgrp >> 1);
        int mb = 0;
        #pragma unroll
        for (int r = 0; r < 4; ++r) mb |= ((int)mask_lds[node][c_of + r]) << r;
        mask4[mt] = mb;
    }

    for (int nt = 0; nt < 8; ++nt) {
        bf16x8 bfrH[4], bfrL[4];
        #pragma unroll
        for (int kt = 0; kt < 4; ++kt) {
            bfrH[kt] = *(const bf16x8*)&WgHi[((nt * 4 + kt) * 64 + lane) * 8];
            bfrL[kt] = *(const bf16x8*)&WgLo[((nt * 4 + kt) * 64 + lane) * 8];
        }
        #pragma unroll
        for (int mt = 0; mt < 2; ++mt) {
            f32x4 acc = {0.f, 0.f, 0.f, 0.f};
            #pragma unroll
            for (int kt = 0; kt < 4; ++kt) {
                acc = __builtin_amdgcn_mfma_f32_16x16x32_bf16(afrH[mt][kt], bfrH[kt], acc, 0, 0, 0);
                acc = __builtin_amdgcn_mfma_f32_16x16x32_bf16(afrH[mt][kt], bfrL[kt], acc, 0, 0, 0);
                acc = __builtin_amdgcn_mfma_f32_16x16x32_bf16(afrL[mt][kt], bfrH[kt], acc, 0, 0, 0);
            }
            // relu + masked max over this lane's 4 rows
            float m4 = -FLT_MAX;
            #pragma unroll
            for (int r = 0; r < 4; ++r)
                if (mask4[mt] & (1 << r)) m4 = fmaxf(m4, fmaxf(acc[r], 0.f));
            const float mv = fmaxf(m4, __shfl_xor(m4, 16));
            if ((lgrp & 1) == 0) {  // lgrp 0 writes node0, lgrp 2 writes node1
                const int node = (w * 2 + mt) * 2 + (lgrp >> 1);
                const float p = anyc_lds[node] ? mv : 0.f;
                const unsigned short ph = f2bfbits(p);
                const unsigned short pl = f2bfbits(p - bfbits2f(ph));
                const unsigned off = SWZ(node, (nt * 16 + lrow) * 2);
                *(unsigned short*)&pH[off] = ph;
                *(unsigned short*)&pL[off] = pl;
            }
        }
    }
    __syncthreads();

    // --- GEMM-D: h = tanh([x|pooled] @ [Wih;Whh] + b), split-bf16 ---
    bf16x8 ah[8], al[8];
    #pragma unroll
    for (int kt = 0; kt < 4; ++kt) {   // x part, direct global + split cvt
        const float* src = &x_l[(nbase + lrow) * FF + kt * 32 + lgrp * 8];
        const float4 v0 = *(const float4*)src;
        const float4 v1 = *(const float4*)(src + 4);
        const float vv[8] = {v0.x, v0.y, v0.z, v0.w, v1.x, v1.y, v1.z, v1.w};
        bf16x8 hfr, lfr;
        #pragma unroll
        for (int i = 0; i < 8; ++i) {
            const __bf16 hb = (__bf16)vv[i];
            hfr[i] = hb;
            lfr[i] = (__bf16)(vv[i] - (float)hb);
        }
        ah[kt] = hfr; al[kt] = lfr;
    }
    #pragma unroll
    for (int kt = 4; kt < 8; ++kt) {   // pooled part from LDS
        const unsigned off = SWZ(lrow, (kt - 4) * 64 + lgrp * 16);
        ah[kt] = *(const bf16x8*)&pH[off];
        al[kt] = *(const bf16x8*)&pL[off];
    }
    #pragma unroll
    for (int nn = 0; nn < 2; ++nn) {
        const int nt = w * 2 + nn;
        f32x4 acc = {0.f, 0.f, 0.f, 0.f};
        #pragma unroll
        for (int kt = 0; kt < 8; ++kt) {
            const bf16x8 bh = *(const bf16x8*)&WdHi[((nt * 8 + kt) * 64 + lane) * 8];
            const bf16x8 bl = *(const bf16x8*)&WdLo[((nt * 8 + kt) * 64 + lane) * 8];
            acc = __builtin_amdgcn_mfma_f32_16x16x32_bf16(ah[kt], bh, acc, 0, 0, 0);
            acc = __builtin_amdgcn_mfma_f32_16x16x32_bf16(ah[kt], bl, acc, 0, 0, 0);
            acc = __builtin_amdgcn_mfma_f32_16x16x32_bf16(al[kt], bh, acc, 0, 0, 0);
        }
        const float b = bias[nt * 16 + lrow];
        #pragma unroll
        for (int r = 0; r < 4; ++r) {
            const int node = lgrp * 4 + r;
            h_out[(nbase + node) * HH + nt * 16 + lrow] = tanhf(acc[r] + b);
        }
    }
}

extern "C" void kernel_launch(void* const* d_in, const int* in_sizes, int n_in,
                              void* d_out, int out_size, void* d_ws, size_t ws_size,
                              hipStream_t stream) {
    const float* node_features = (const float*)d_in[0];
    const int*   child_idx     = (const int*)d_in[1];
    const unsigned char* child_mask_raw = (const unsigned char*)d_in[2];
    const float* A_c  = (const float*)d_in[3];
    const float* Wg   = (const float*)d_in[4];
    const float* Wih  = (const float*)d_in[5];
    const float* Whh  = (const float*)d_in[6];
    const float* bih  = (const float*)d_in[7];
    const float* bhh  = (const float*)d_in[8];
    float* out = (float*)d_out;

    char* ws = (char*)d_ws;
    int* flag = (int*)ws;
    unsigned char* mask_u8 = (unsigned char*)(ws + 256);            // 768 KB
    unsigned short* WgHi = (unsigned short*)(ws + (1 << 20));               // 32 KB
    unsigned short* WgLo = (unsigned short*)(ws + (1 << 20) + (32 << 10));  // 32 KB
    unsigned short* WdHi = (unsigned short*)(ws + (1 << 20) + (64 << 10));  // 64 KB
    unsigned short* WdLo = (unsigned short*)(ws + (1 << 20) + (128 << 10)); // 64 KB
    float* bias          = (float*)(ws + (1 << 20) + (192 << 10));
    float* hbuf          = (float*)(ws + (1 << 20) + (256 << 10));          // 8 MB

    detect_mask_kernel<<<1, 256, 0, stream>>>(child_mask_raw, flag);
    convert_mask_kernel<<<(LL * NN * CC + 255) / 256, 256, 0, stream>>>(
        child_mask_raw, flag, mask_u8);
    pack_weights_kernel<<<25, 256, 0, stream>>>(Wg, Wih, Whh, bih, bhh,
                                                WgHi, WgLo, WdHi, WdLo, bias);

    // Levels reversed; level L-1 has all-false masks so h_prev never read.
    const float* hp = hbuf;
    for (int s = 0; s < LL; ++s) {
        const int l = LL - 1 - s;
        float* ho = (s & 1) ? out : hbuf;
        level_kernel<<<NN / BN, 256, 0, stream>>>(
            node_features + (size_t)l * NN * FF,
            child_idx     + (size_t)l * NN * CC,
            mask_u8       + (size_t)l * NN * CC,
            A_c           + (size_t)l * NN * CC * CC,
            WgHi, WgLo, WdHi, WdLo, bias,
            hp, ho);
        hp = ho;
    }
}

// Round 4
// 215.166 us; speedup vs baseline: 4.4351x; 1.4913x over previous
//
#include <hip/hip_runtime.h>
#include <cfloat>

// Problem constants: L=6, N=16384, C=8, F=128, H=128
#define LL 6
#define NN 16384
#define CC 8
#define FF 128
#define HH 128
#define BN 16   // nodes per block

typedef __bf16 bf16x8 __attribute__((ext_vector_type(8)));
typedef __attribute__((ext_vector_type(4))) float f32x4;

static __device__ inline unsigned short f2bfbits(float f) {
    return __builtin_bit_cast(unsigned short, (__bf16)f);
}
static __device__ inline float bfbits2f(unsigned short b) {
    return (float)__builtin_bit_cast(__bf16, b);
}

// ---------------------------------------------------------------------------
// child_mask dtype detection (bool may arrive as u8 or int32). int32 0/1 LE
// values have all bytes at offset %4!=0 zero -> (v & 0xFFFFFF00)==0 for every
// dword. Byte-layout random 0/1 bytes violate that w.p. 7/8 per dword.
// Scan 2048 B (512 dwords) fully in parallel: ~2 us. flag=1 -> int32 layout.
// ---------------------------------------------------------------------------
__global__ void detect_mask_kernel(const unsigned int* __restrict__ raw,
                                   int* __restrict__ flag) {
    __shared__ int any;
    if (threadIdx.x == 0) any = 0;
    __syncthreads();
    const unsigned int a = raw[threadIdx.x * 2 + 0];
    const unsigned int b = raw[threadIdx.x * 2 + 1];
    if (((a | b) & 0xFFFFFF00u) != 0) atomicOr(&any, 1);
    __syncthreads();
    if (threadIdx.x == 0) *flag = any ? 0 : 1;
}

// Canonicalize mask to u8, 4 elements per thread.
__global__ void convert_mask_kernel(const unsigned char* __restrict__ raw,
                                    const int* __restrict__ flag,
                                    unsigned char* __restrict__ mask_u8) {
    const int j = blockIdx.x * blockDim.x + threadIdx.x;
    if (j >= LL * NN * CC / 4) return;
    const int f = *flag;
    uchar4 o;
    if (f) {
        const uint4 v = *(const uint4*)(raw + (size_t)j * 16);
        o.x = v.x ? 1 : 0; o.y = v.y ? 1 : 0; o.z = v.z ? 1 : 0; o.w = v.w ? 1 : 0;
    } else {
        const unsigned v = *(const unsigned*)(raw + (size_t)j * 4);
        o.x = (v & 0xFFu) ? 1 : 0;
        o.y = (v & 0xFF00u) ? 1 : 0;
        o.z = (v & 0xFF0000u) ? 1 : 0;
        o.w = (v >> 24) ? 1 : 0;
    }
    *(uchar4*)(mask_u8 + (size_t)j * 4) = o;
}

// ---------------------------------------------------------------------------
// One-time weight packing into MFMA B-fragment order, split hi/lo bf16.
// B-frag (16x16x32): lane l supplies B[k][n], n = l&15, k = 8*(l>>4)+i.
// WgHi/WgLo : [nt(8)][kt(4)][lane(64)][i(8)] of Wg
// WdHi/WdLo : [nt(8)][kt(8)][lane(64)][i(8)] of [Wih;Whh]
// ---------------------------------------------------------------------------
__global__ void pack_weights_kernel(const float* __restrict__ Wg,
                                    const float* __restrict__ Wih,
                                    const float* __restrict__ Whh,
                                    const float* __restrict__ bih,
                                    const float* __restrict__ bhh,
                                    unsigned short* __restrict__ WgHi,
                                    unsigned short* __restrict__ WgLo,
                                    unsigned short* __restrict__ WdHi,
                                    unsigned short* __restrict__ WdLo,
                                    float* __restrict__ bias) {
    const int t = blockIdx.x * 256 + threadIdx.x;
    if (t < 2048) {                      // Wg: (nt*4+kt)*64+lane == t
        const int l = t & 63;
        const int nt = t >> 8;
        const int kt = (t >> 6) & 3;
        const int n = nt * 16 + (l & 15);
        const int kb = kt * 32 + (l >> 4) * 8;
        #pragma unroll
        for (int i = 0; i < 8; ++i) {
            const float v = Wg[(kb + i) * HH + n];
            const unsigned short hb = f2bfbits(v);
            WgHi[t * 8 + i] = hb;
            WgLo[t * 8 + i] = f2bfbits(v - bfbits2f(hb));
        }
    } else if (t < 6144) {               // Wd: u = (nt*8+kt)*64+lane
        const int u = t - 2048;
        const int l = u & 63;
        const int nt = u >> 9;
        const int kt = (u >> 6) & 7;
        const int n = nt * 16 + (l & 15);
        const int kb = (kt & 3) * 32 + (l >> 4) * 8;
        const float* W = (kt < 4) ? Wih : Whh;
        #pragma unroll
        for (int i = 0; i < 8; ++i) {
            const float v = W[(kb + i) * HH + n];
            const unsigned short hb = f2bfbits(v);
            WdHi[u * 8 + i] = hb;
            WdLo[u * 8 + i] = f2bfbits(v - bfbits2f(hb));
        }
    } else if (t < 6272) {
        const int n = t - 6144;
        bias[n] = bih[n] + bhh[n];
    }
}

// byte-offset swizzle for 256B-stride rows (breaks 16-way bank conflict)
#define SWZ(row, byte) ((unsigned)(((row) * 256 + (byte)) ^ (((row) & 7) << 4)))

// ---------------------------------------------------------------------------
// One level, fused. Block: 256 threads = 4 waves; BN=16 nodes.
// Phase A (per-wave 4 nodes): gather + 8x8 mix (fp32) -> t split-bf16 in LDS.
// GEMM-B (nt-split: wave owns 2 col-tiles, loops all 8 M-tiles from LDS,
//         Wg frags hoisted in regs): relu + masked maxpool in-register.
// GEMM-D: [x|pooled] @ [Wih;Whh] split-bf16, tanh, store.
// Empty nodes skip phase A; empty blocks skip GEMM-B + pooled half of GEMM-D.
// ---------------------------------------------------------------------------
__global__ __launch_bounds__(256) void level_kernel(
    const float* __restrict__ x_l,            // [N][F]
    const int* __restrict__ cidx_l,           // [N][C]
    const unsigned char* __restrict__ mask_l, // [N][C] u8
    const float* __restrict__ a_l,            // [N][C][C]
    const unsigned short* __restrict__ WgHi,
    const unsigned short* __restrict__ WgLo,
    const unsigned short* __restrict__ WdHi,
    const unsigned short* __restrict__ WdLo,
    const float* __restrict__ bias,
    const float* __restrict__ h_prev,         // [N][H]
    float* __restrict__ h_out)                // [N][H]
{
    __shared__ __align__(16) unsigned char tH_raw[BN * CC * 256];  // 32 KB
    __shared__ __align__(16) unsigned char tL_raw[BN * CC * 256];  // 32 KB
    __shared__ __align__(16) unsigned char pH[BN * 256];           // 4 KB
    __shared__ __align__(16) unsigned char pL[BN * 256];           // 4 KB
    __shared__ float a_lds[BN][CC][CC];                            // 4 KB
    __shared__ int   cidx_lds[BN][CC];
    __shared__ __align__(16) unsigned char maskbyte[BN];           // per-node bitmask

    const int tid = threadIdx.x;
    const int lane = tid & 63;
    const int w = tid >> 6;
    const int lrow = lane & 15, lgrp = lane >> 4;
    const long nbase = (long)blockIdx.x * BN;

    // --- stage per-node small data (vectorized) ---
    ((float4*)a_lds)[tid] = ((const float4*)(a_l + nbase * CC * CC))[tid];  // 1024 f
    if (tid < 32)
        ((uint4*)cidx_lds)[tid] = ((const uint4*)(cidx_l + nbase * CC))[tid];
    if (tid < BN) {
        unsigned char mb = 0;
        #pragma unroll
        for (int c = 0; c < CC; ++c)
            mb |= mask_l[nbase * CC + tid * CC + c] << c;
        maskbyte[tid] = mb;
    }

    // --- early x loads (raw fp32, consumed in GEMM-D) ---
    float4 xr[8];
    #pragma unroll
    for (int kt = 0; kt < 4; ++kt) {
        const float* src = &x_l[(nbase + lrow) * FF + kt * 32 + lgrp * 8];
        xr[kt * 2 + 0] = *(const float4*)src;
        xr[kt * 2 + 1] = *(const float4*)(src + 4);
    }
    __syncthreads();

    // --- Phase A: gather + 8x8 mix (fp32), write t split-bf16 ---
    // wave w owns nodes w*4..w*4+3; lane owns column pair (2*lane, 2*lane+1)
    for (int nl = 0; nl < 4; ++nl) {
        const int node = w * 4 + nl;
        const int mb = maskbyte[node];           // wave-uniform
        if (!mb) continue;                        // empty node: skip entirely
        float c0[CC], c1[CC];
        #pragma unroll
        for (int c = 0; c < CC; ++c) {
            float a0 = 0.f, a1 = 0.f;
            if (mb & (1 << c)) {
                const float2 v = *(const float2*)&h_prev[(long)cidx_lds[node][c] * HH + 2 * lane];
                a0 = v.x; a1 = v.y;
            }
            c0[c] = a0; c1[c] = a1;
        }
        #pragma unroll
        for (int c = 0; c < CC; ++c) {
            float s0 = 0.f, s1 = 0.f;
            #pragma unroll
            for (int d = 0; d < CC; ++d) {
                const float av = a_lds[node][c][d];
                s0 += av * c0[d]; s1 += av * c1[d];
            }
            const int row = node * CC + c;
            const unsigned short h0 = f2bfbits(s0);
            const unsigned short h1 = f2bfbits(s1);
            const unsigned short l0 = f2bfbits(s0 - bfbits2f(h0));
            const unsigned short l1 = f2bfbits(s1 - bfbits2f(h1));
            const unsigned off = SWZ(row, lane * 4);
            *(unsigned*)&tH_raw[off] = (unsigned)h0 | ((unsigned)h1 << 16);
            *(unsigned*)&tL_raw[off] = (unsigned)l0 | ((unsigned)l1 << 16);
        }
    }
    __syncthreads();

    // block-uniform "any child in block" (broadcast LDS read)
    const uint4 mball = *(const uint4*)maskbyte;
    const int any = (mball.x | mball.y | mball.z | mball.w) != 0;

    // --- GEMM-B: g = relu(t @ Wg) split-bf16 + masked maxpool ---
    // wave owns col-tiles nt = w*2, w*2+1; loops all 8 M-tiles.
    if (any) {
        bf16x8 bgH[2][4], bgL[2][4];
        #pragma unroll
        for (int nn = 0; nn < 2; ++nn)
            #pragma unroll
            for (int kt = 0; kt < 4; ++kt) {
                const int fo = (((w * 2 + nn) * 4 + kt) * 64 + lane) * 8;
                bgH[nn][kt] = *(const bf16x8*)&WgHi[fo];
                bgL[nn][kt] = *(const bf16x8*)&WgLo[fo];
            }
        const int c_of = (lgrp & 1) * 4;
        #pragma unroll
        for (int mtg = 0; mtg < 8; ++mtg) {
            bf16x8 aH[4], aL[4];
            #pragma unroll
            for (int kt = 0; kt < 4; ++kt) {
                const unsigned off = SWZ(mtg * 16 + lrow, kt * 64 + lgrp * 16);
                aH[kt] = *(const bf16x8*)&tH_raw[off];
                aL[kt] = *(const bf16x8*)&tL_raw[off];
            }
            const int node = mtg * 2 + (lgrp >> 1);
            const int nmb = maskbyte[node];
            const int mb4 = (nmb >> c_of) & 15;
            #pragma unroll
            for (int nn = 0; nn < 2; ++nn) {
                f32x4 acc = {0.f, 0.f, 0.f, 0.f};
                #pragma unroll
                for (int kt = 0; kt < 4; ++kt) {
                    acc = __builtin_amdgcn_mfma_f32_16x16x32_bf16(aH[kt], bgH[nn][kt], acc, 0, 0, 0);
                    acc = __builtin_amdgcn_mfma_f32_16x16x32_bf16(aH[kt], bgL[nn][kt], acc, 0, 0, 0);
                    acc = __builtin_amdgcn_mfma_f32_16x16x32_bf16(aL[kt], bgH[nn][kt], acc, 0, 0, 0);
                }
                float m4 = -FLT_MAX;
                #pragma unroll
                for (int r = 0; r < 4; ++r)
                    if (mb4 & (1 << r)) m4 = fmaxf(m4, fmaxf(acc[r], 0.f));
                const float mv = fmaxf(m4, __shfl_xor(m4, 16));
                if ((lgrp & 1) == 0) {   // lgrp 0 -> even node, lgrp 2 -> odd node
                    const float p = nmb ? mv : 0.f;
                    const unsigned short ph = f2bfbits(p);
                    const unsigned short pl = f2bfbits(p - bfbits2f(ph));
                    const unsigned off = SWZ(node, ((w * 2 + nn) * 16 + lrow) * 2);
                    *(unsigned short*)&pH[off] = ph;
                    *(unsigned short*)&pL[off] = pl;
                }
            }
        }
        __syncthreads();
    }

    // --- GEMM-D: h = tanh([x|pooled] @ [Wih;Whh] + b), split-bf16 ---
    bf16x8 ah[8], al[8];
    #pragma unroll
    for (int kt = 0; kt < 4; ++kt) {   // x part from preloaded registers
        const float4 v0 = xr[kt * 2 + 0];
        const float4 v1 = xr[kt * 2 + 1];
        const float vv[8] = {v0.x, v0.y, v0.z, v0.w, v1.x, v1.y, v1.z, v1.w};
        bf16x8 hfr, lfr;
        #pragma unroll
        for (int i = 0; i < 8; ++i) {
            const __bf16 hb = (__bf16)vv[i];
            hfr[i] = hb;
            lfr[i] = (__bf16)(vv[i] - (float)hb);
        }
        ah[kt] = hfr; al[kt] = lfr;
    }
    if (any) {
        #pragma unroll
        for (int kt = 4; kt < 8; ++kt) {   // pooled part from LDS
            const unsigned off = SWZ(lrow, (kt - 4) * 64 + lgrp * 16);
            ah[kt] = *(const bf16x8*)&pH[off];
            al[kt] = *(const bf16x8*)&pL[off];
        }
    }
    #pragma unroll
    for (int nn = 0; nn < 2; ++nn) {
        const int nt = w * 2 + nn;
        f32x4 acc = {0.f, 0.f, 0.f, 0.f};
        #pragma unroll
        for (int kt = 0; kt < 4; ++kt) {
            const bf16x8 bh = *(const bf16x8*)&WdHi[((nt * 8 + kt) * 64 + lane) * 8];
            const bf16x8 bl = *(const bf16x8*)&WdLo[((nt * 8 + kt) * 64 + lane) * 8];
            acc = __builtin_amdgcn_mfma_f32_16x16x32_bf16(ah[kt], bh, acc, 0, 0, 0);
            acc = __builtin_amdgcn_mfma_f32_16x16x32_bf16(ah[kt], bl, acc, 0, 0, 0);
            acc = __builtin_amdgcn_mfma_f32_16x16x32_bf16(al[kt], bh, acc, 0, 0, 0);
        }
        if (any) {
            #pragma unroll
            for (int kt = 4; kt < 8; ++kt) {
                const bf16x8 bh = *(const bf16x8*)&WdHi[((nt * 8 + kt) * 64 + lane) * 8];
                const bf16x8 bl = *(const bf16x8*)&WdLo[((nt * 8 + kt) * 64 + lane) * 8];
                acc = __builtin_amdgcn_mfma_f32_16x16x32_bf16(ah[kt], bh, acc, 0, 0, 0);
                acc = __builtin_amdgcn_mfma_f32_16x16x32_bf16(ah[kt], bl, acc, 0, 0, 0);
                acc = __builtin_amdgcn_mfma_f32_16x16x32_bf16(al[kt], bh, acc, 0, 0, 0);
            }
        }
        const float b = bias[nt * 16 + lrow];
        #pragma unroll
        for (int r = 0; r < 4; ++r) {
            const int node = lgrp * 4 + r;
            h_out[(nbase + node) * HH + nt * 16 + lrow] = tanhf(acc[r] + b);
        }
    }
}

extern "C" void kernel_launch(void* const* d_in, const int* in_sizes, int n_in,
                              void* d_out, int out_size, void* d_ws, size_t ws_size,
                              hipStream_t stream) {
    const float* node_features = (const float*)d_in[0];
    const int*   child_idx     = (const int*)d_in[1];
    const unsigned char* child_mask_raw = (const unsigned char*)d_in[2];
    const float* A_c  = (const float*)d_in[3];
    const float* Wg   = (const float*)d_in[4];
    const float* Wih  = (const float*)d_in[5];
    const float* Whh  = (const float*)d_in[6];
    const float* bih  = (const float*)d_in[7];
    const float* bhh  = (const float*)d_in[8];
    float* out = (float*)d_out;

    char* ws = (char*)d_ws;
    int* flag = (int*)ws;
    unsigned char* mask_u8 = (unsigned char*)(ws + 256);                    // 768 KB
    unsigned short* WgHi = (unsigned short*)(ws + (1 << 20));               // 32 KB
    unsigned short* WgLo = (unsigned short*)(ws + (1 << 20) + (32 << 10));  // 32 KB
    unsigned short* WdHi = (unsigned short*)(ws + (1 << 20) + (64 << 10));  // 64 KB
    unsigned short* WdLo = (unsigned short*)(ws + (1 << 20) + (128 << 10)); // 64 KB
    float* bias          = (float*)(ws + (1 << 20) + (192 << 10));
    float* hbuf          = (float*)(ws + (1 << 20) + (256 << 10));          // 8 MB

    detect_mask_kernel<<<1, 256, 0, stream>>>((const unsigned int*)child_mask_raw, flag);
    convert_mask_kernel<<<(LL * NN * CC / 4 + 255) / 256, 256, 0, stream>>>(
        child_mask_raw, flag, mask_u8);
    pack_weights_kernel<<<25, 256, 0, stream>>>(Wg, Wih, Whh, bih, bhh,
                                                WgHi, WgLo, WdHi, WdLo, bias);

    // Levels reversed; level L-1 has all-false masks so h_prev never read.
    const float* hp = hbuf;
    for (int s = 0; s < LL; ++s) {
        const int l = LL - 1 - s;
        float* ho = (s & 1) ? out : hbuf;
        level_kernel<<<NN / BN, 256, 0, stream>>>(
            node_features + (size_t)l * NN * FF,
            child_idx     + (size_t)l * NN * CC,
            mask_u8       + (size_t)l * NN * CC,
            A_c           + (size_t)l * NN * CC * CC,
            WgHi, WgLo, WdHi, WdLo, bias,
            hp, ho);
        hp = ho;
    }
}

// Round 5
// 204.429 us; speedup vs baseline: 4.6680x; 1.0525x over previous
//
#include <hip/hip_runtime.h>
#include <cfloat>

// Problem constants: L=6, N=16384, C=8, F=128, H=128
#define LL 6
#define NN 16384
#define CC 8
#define FF 128
#define HH 128
#define BN 16   // nodes per block (level kernel)

typedef __bf16 bf16x8 __attribute__((ext_vector_type(8)));
typedef __attribute__((ext_vector_type(4))) float f32x4;

static __device__ inline unsigned short f2bfbits(float f) {
    return __builtin_bit_cast(unsigned short, (__bf16)f);
}
static __device__ inline float bfbits2f(unsigned short b) {
    return (float)__builtin_bit_cast(__bf16, b);
}

// ---------------------------------------------------------------------------
// child_mask dtype detection (bool may arrive as u8 or int32). int32 0/1 LE
// values have all bytes at offset %4!=0 zero. Byte-layout random 0/1 bytes
// violate that w.p. 7/8 per dword. Parallel 2048 B scan. flag=1 -> int32.
// ---------------------------------------------------------------------------
__global__ void detect_mask_kernel(const unsigned int* __restrict__ raw,
                                   int* __restrict__ flag) {
    __shared__ int any;
    if (threadIdx.x == 0) any = 0;
    __syncthreads();
    const unsigned int a = raw[threadIdx.x * 2 + 0];
    const unsigned int b = raw[threadIdx.x * 2 + 1];
    if (((a | b) & 0xFFFFFF00u) != 0) atomicOr(&any, 1);
    __syncthreads();
    if (threadIdx.x == 0) *flag = any ? 0 : 1;
}

// Per-node 8-bit child mask, one thread per node.
__global__ void mask_bits_kernel(const unsigned char* __restrict__ raw,
                                 const int* __restrict__ flag,
                                 unsigned char* __restrict__ mbits) {
    const int n = blockIdx.x * blockDim.x + threadIdx.x;
    if (n >= LL * NN) return;
    const int f = *flag;
    unsigned char b;
    if (f) {
        const uint4 v0 = *(const uint4*)(raw + (size_t)n * 32);
        const uint4 v1 = *(const uint4*)(raw + (size_t)n * 32 + 16);
        b = (v0.x ? 1 : 0) | (v0.y ? 2 : 0) | (v0.z ? 4 : 0) | (v0.w ? 8 : 0)
          | (v1.x ? 16 : 0) | (v1.y ? 32 : 0) | (v1.z ? 64 : 0) | (v1.w ? 128 : 0);
    } else {
        const unsigned a = *(const unsigned*)(raw + (size_t)n * 8);
        const unsigned c = *(const unsigned*)(raw + (size_t)n * 8 + 4);
        b = ((a & 0xFFu) ? 1 : 0) | ((a & 0xFF00u) ? 2 : 0)
          | ((a & 0xFF0000u) ? 4 : 0) | ((a >> 24) ? 8 : 0)
          | ((c & 0xFFu) ? 16 : 0) | ((c & 0xFF00u) ? 32 : 0)
          | ((c & 0xFF0000u) ? 64 : 0) | ((c >> 24) ? 128 : 0);
    }
    mbits[n] = b;
}

// ---------------------------------------------------------------------------
// One-time weight packing into MFMA B-fragment order, split hi/lo bf16.
// B-frag (16x16x32): lane l supplies B[k][n], n = l&15, k = 8*(l>>4)+i.
// WgHi/WgLo : [nt(8)][kt(4)][lane(64)][i(8)] of Wg
// WdHi/WdLo : [nt(8)][kt(8)][lane(64)][i(8)] of [Wih;Whh]
// ---------------------------------------------------------------------------
__global__ void pack_weights_kernel(const float* __restrict__ Wg,
                                    const float* __restrict__ Wih,
                                    const float* __restrict__ Whh,
                                    const float* __restrict__ bih,
                                    const float* __restrict__ bhh,
                                    unsigned short* __restrict__ WgHi,
                                    unsigned short* __restrict__ WgLo,
                                    unsigned short* __restrict__ WdHi,
                                    unsigned short* __restrict__ WdLo,
                                    float* __restrict__ bias) {
    const int t = blockIdx.x * 256 + threadIdx.x;
    if (t < 2048) {                      // Wg: (nt*4+kt)*64+lane == t
        const int l = t & 63;
        const int nt = t >> 8;
        const int kt = (t >> 6) & 3;
        const int n = nt * 16 + (l & 15);
        const int kb = kt * 32 + (l >> 4) * 8;
        #pragma unroll
        for (int i = 0; i < 8; ++i) {
            const float v = Wg[(kb + i) * HH + n];
            const unsigned short hb = f2bfbits(v);
            WgHi[t * 8 + i] = hb;
            WgLo[t * 8 + i] = f2bfbits(v - bfbits2f(hb));
        }
    } else if (t < 6144) {               // Wd: u = (nt*8+kt)*64+lane
        const int u = t - 2048;
        const int l = u & 63;
        const int nt = u >> 9;
        const int kt = (u >> 6) & 7;
        const int n = nt * 16 + (l & 15);
        const int kb = (kt & 3) * 32 + (l >> 4) * 8;
        const float* W = (kt < 4) ? Wih : Whh;
        #pragma unroll
        for (int i = 0; i < 8; ++i) {
            const float v = W[(kb + i) * HH + n];
            const unsigned short hb = f2bfbits(v);
            WdHi[u * 8 + i] = hb;
            WdLo[u * 8 + i] = f2bfbits(v - bfbits2f(hb));
        }
    } else if (t < 6272) {
        const int n = t - 6144;
        bias[n] = bih[n] + bhh[n];
    }
}

// ---------------------------------------------------------------------------
// Per-level precompute: Hp = h_prev @ Wg, split-bf16 (== fp32 accurate).
// Block: 256 threads = 4 waves; 64 rows per block, wave owns 16 rows.
// ---------------------------------------------------------------------------
__global__ __launch_bounds__(256) void gemm_wg_kernel(
    const float* __restrict__ h,          // [N][H]
    const unsigned short* __restrict__ WgHi,
    const unsigned short* __restrict__ WgLo,
    float* __restrict__ Hp)               // [N][H]
{
    const int lane = threadIdx.x & 63;
    const int w = threadIdx.x >> 6;
    const int lrow = lane & 15, lgrp = lane >> 4;
    const int rbase = blockIdx.x * 64 + w * 16;

    bf16x8 aH[4], aL[4];
    #pragma unroll
    for (int kt = 0; kt < 4; ++kt) {
        const float* src = &h[(size_t)(rbase + lrow) * HH + kt * 32 + lgrp * 8];
        const float4 v0 = *(const float4*)src;
        const float4 v1 = *(const float4*)(src + 4);
        const float vv[8] = {v0.x, v0.y, v0.z, v0.w, v1.x, v1.y, v1.z, v1.w};
        bf16x8 hf, lf;
        #pragma unroll
        for (int i = 0; i < 8; ++i) {
            const __bf16 hb = (__bf16)vv[i];
            hf[i] = hb;
            lf[i] = (__bf16)(vv[i] - (float)hb);
        }
        aH[kt] = hf; aL[kt] = lf;
    }
    #pragma unroll
    for (int nt = 0; nt < 8; ++nt) {
        f32x4 acc = {0.f, 0.f, 0.f, 0.f};
        #pragma unroll
        for (int kt = 0; kt < 4; ++kt) {
            const bf16x8 bh = *(const bf16x8*)&WgHi[((nt * 4 + kt) * 64 + lane) * 8];
            const bf16x8 bl = *(const bf16x8*)&WgLo[((nt * 4 + kt) * 64 + lane) * 8];
            acc = __builtin_amdgcn_mfma_f32_16x16x32_bf16(aH[kt], bh, acc, 0, 0, 0);
            acc = __builtin_amdgcn_mfma_f32_16x16x32_bf16(aH[kt], bl, acc, 0, 0, 0);
            acc = __builtin_amdgcn_mfma_f32_16x16x32_bf16(aL[kt], bh, acc, 0, 0, 0);
        }
        #pragma unroll
        for (int r = 0; r < 4; ++r)
            Hp[(size_t)(rbase + lgrp * 4 + r) * HH + nt * 16 + lrow] = acc[r];
    }
}

// byte-offset swizzle for 256B-stride rows (breaks 16-way bank conflict)
#define SWZ(row, byte) ((unsigned)(((row) * 256 + (byte)) ^ (((row) & 7) << 4)))

// ---------------------------------------------------------------------------
// One level. Block: 256 threads = 4 waves; BN=16 nodes.
// Phase A (wave owns 4 nodes, lane owns cols 2l,2l+1): gather Hp rows of
// masked children, 8x8 mix in fp32 (A_c @ (ch@Wg) == (A_c@ch)@Wg), relu +
// masked maxpool in-register -> pooled split-bf16 in LDS.
// GEMM-D: [x|pooled] @ [Wih;Whh] split-bf16, tanh, store.
// Empty nodes write pooled=0; all-empty blocks skip phase A and pooled MFMAs.
// ---------------------------------------------------------------------------
__global__ __launch_bounds__(256) void level_kernel(
    const float* __restrict__ x_l,            // [N][F]
    const int* __restrict__ cidx_l,           // [N][C]
    const unsigned char* __restrict__ mbits_l,// [N] child bitmask
    const float* __restrict__ Hp,             // [N][H] = h_prev @ Wg
    const float* __restrict__ a_l,            // [N][C][C]
    const unsigned short* __restrict__ WdHi,
    const unsigned short* __restrict__ WdLo,
    const float* __restrict__ bias,
    float* __restrict__ h_out)                // [N][H]
{
    __shared__ __align__(16) unsigned char pH[BN * 256];   // 4 KB pooled hi
    __shared__ __align__(16) unsigned char pL[BN * 256];   // 4 KB pooled lo
    __shared__ float a_lds[BN][CC][CC];                    // 4 KB
    __shared__ int   cidx_lds[BN][CC];
    __shared__ __align__(16) unsigned char maskbyte[BN];

    const int tid = threadIdx.x;
    const int lane = tid & 63;
    const int w = tid >> 6;
    const int lrow = lane & 15, lgrp = lane >> 4;
    const long nbase = (long)blockIdx.x * BN;

    // --- stage per-node small data ---
    ((float4*)a_lds)[tid] = ((const float4*)(a_l + nbase * CC * CC))[tid];
    if (tid < 32)
        ((uint4*)cidx_lds)[tid] = ((const uint4*)(cidx_l + nbase * CC))[tid];
    if (tid < BN) maskbyte[tid] = mbits_l[nbase + tid];

    // --- early x loads (raw fp32, consumed in GEMM-D) ---
    float4 xr[8];
    #pragma unroll
    for (int kt = 0; kt < 4; ++kt) {
        const float* src = &x_l[(nbase + lrow) * FF + kt * 32 + lgrp * 8];
        xr[kt * 2 + 0] = *(const float4*)src;
        xr[kt * 2 + 1] = *(const float4*)(src + 4);
    }
    __syncthreads();

    const uint4 mball = *(const uint4*)maskbyte;
    const int any = (mball.x | mball.y | mball.z | mball.w) != 0;  // block-uniform

    // --- Phase A: gather Hp + 8x8 mix + relu + masked maxpool -> pooled ---
    if (any) {
        for (int nl = 0; nl < 4; ++nl) {
            const int node = w * 4 + nl;
            const int mb = maskbyte[node];           // wave-uniform
            float m0 = 0.f, m1 = 0.f;
            if (mb) {
                float c0[CC], c1[CC];
                #pragma unroll
                for (int c = 0; c < CC; ++c) { c0[c] = 0.f; c1[c] = 0.f; }
                #pragma unroll
                for (int c = 0; c < CC; ++c) {
                    if (mb & (1 << c)) {
                        const float2 v = *(const float2*)&Hp[(size_t)cidx_lds[node][c] * HH + 2 * lane];
                        c0[c] = v.x; c1[c] = v.y;
                    }
                }
                float mm0 = -FLT_MAX, mm1 = -FLT_MAX;
                #pragma unroll
                for (int c = 0; c < CC; ++c) {
                    if (mb & (1 << c)) {
                        float s0 = 0.f, s1 = 0.f;
                        #pragma unroll
                        for (int d = 0; d < CC; ++d) {
                            const float av = a_lds[node][c][d];
                            s0 += av * c0[d]; s1 += av * c1[d];
                        }
                        mm0 = fmaxf(mm0, fmaxf(s0, 0.f));
                        mm1 = fmaxf(mm1, fmaxf(s1, 0.f));
                    }
                }
                m0 = mm0; m1 = mm1;
            }
            const unsigned short h0 = f2bfbits(m0);
            const unsigned short h1 = f2bfbits(m1);
            const unsigned short l0 = f2bfbits(m0 - bfbits2f(h0));
            const unsigned short l1 = f2bfbits(m1 - bfbits2f(h1));
            const unsigned off = SWZ(node, lane * 4);   // cols 2*lane, 2*lane+1
            *(unsigned*)&pH[off] = (unsigned)h0 | ((unsigned)h1 << 16);
            *(unsigned*)&pL[off] = (unsigned)l0 | ((unsigned)l1 << 16);
        }
        __syncthreads();
    }

    // --- GEMM-D: h = tanh([x|pooled] @ [Wih;Whh] + b), split-bf16 ---
    bf16x8 ah[8], al[8];
    #pragma unroll
    for (int kt = 0; kt < 4; ++kt) {   // x part from preloaded registers
        const float4 v0 = xr[kt * 2 + 0];
        const float4 v1 = xr[kt * 2 + 1];
        const float vv[8] = {v0.x, v0.y, v0.z, v0.w, v1.x, v1.y, v1.z, v1.w};
        bf16x8 hfr, lfr;
        #pragma unroll
        for (int i = 0; i < 8; ++i) {
            const __bf16 hb = (__bf16)vv[i];
            hfr[i] = hb;
            lfr[i] = (__bf16)(vv[i] - (float)hb);
        }
        ah[kt] = hfr; al[kt] = lfr;
    }
    if (any) {
        #pragma unroll
        for (int kt = 4; kt < 8; ++kt) {   // pooled part from LDS
            const unsigned off = SWZ(lrow, (kt - 4) * 64 + lgrp * 16);
            ah[kt] = *(const bf16x8*)&pH[off];
            al[kt] = *(const bf16x8*)&pL[off];
        }
    }
    #pragma unroll
    for (int nn = 0; nn < 2; ++nn) {
        const int nt = w * 2 + nn;
        f32x4 acc = {0.f, 0.f, 0.f, 0.f};
        #pragma unroll
        for (int kt = 0; kt < 4; ++kt) {
            const bf16x8 bh = *(const bf16x8*)&WdHi[((nt * 8 + kt) * 64 + lane) * 8];
            const bf16x8 bl = *(const bf16x8*)&WdLo[((nt * 8 + kt) * 64 + lane) * 8];
            acc = __builtin_amdgcn_mfma_f32_16x16x32_bf16(ah[kt], bh, acc, 0, 0, 0);
            acc = __builtin_amdgcn_mfma_f32_16x16x32_bf16(ah[kt], bl, acc, 0, 0, 0);
            acc = __builtin_amdgcn_mfma_f32_16x16x32_bf16(al[kt], bh, acc, 0, 0, 0);
        }
        if (any) {
            #pragma unroll
            for (int kt = 4; kt < 8; ++kt) {
                const bf16x8 bh = *(const bf16x8*)&WdHi[((nt * 8 + kt) * 64 + lane) * 8];
                const bf16x8 bl = *(const bf16x8*)&WdLo[((nt * 8 + kt) * 64 + lane) * 8];
                acc = __builtin_amdgcn_mfma_f32_16x16x32_bf16(ah[kt], bh, acc, 0, 0, 0);
                acc = __builtin_amdgcn_mfma_f32_16x16x32_bf16(ah[kt], bl, acc, 0, 0, 0);
                acc = __builtin_amdgcn_mfma_f32_16x16x32_bf16(al[kt], bh, acc, 0, 0, 0);
            }
        }
        const float b = bias[nt * 16 + lrow];
        #pragma unroll
        for (int r = 0; r < 4; ++r) {
            const int node = lgrp * 4 + r;
            h_out[(nbase + node) * HH + nt * 16 + lrow] = tanhf(acc[r] + b);
        }
    }
}

extern "C" void kernel_launch(void* const* d_in, const int* in_sizes, int n_in,
                              void* d_out, int out_size, void* d_ws, size_t ws_size,
                              hipStream_t stream) {
    const float* node_features = (const float*)d_in[0];
    const int*   child_idx     = (const int*)d_in[1];
    const unsigned char* child_mask_raw = (const unsigned char*)d_in[2];
    const float* A_c  = (const float*)d_in[3];
    const float* Wg   = (const float*)d_in[4];
    const float* Wih  = (const float*)d_in[5];
    const float* Whh  = (const float*)d_in[6];
    const float* bih  = (const float*)d_in[7];
    const float* bhh  = (const float*)d_in[8];
    float* out = (float*)d_out;

    char* ws = (char*)d_ws;
    int* flag = (int*)ws;
    unsigned char* mbits = (unsigned char*)(ws + 256);                      // 96 KB
    unsigned short* WgHi = (unsigned short*)(ws + (1 << 20));               // 32 KB
    unsigned short* WgLo = (unsigned short*)(ws + (1 << 20) + (32 << 10));  // 32 KB
    unsigned short* WdHi = (unsigned short*)(ws + (1 << 20) + (64 << 10));  // 64 KB
    unsigned short* WdLo = (unsigned short*)(ws + (1 << 20) + (128 << 10)); // 64 KB
    float* bias          = (float*)(ws + (1 << 20) + (192 << 10));
    float* hbuf          = (float*)(ws + (1 << 20) + (256 << 10));          // 8 MB
    float* Hp            = (float*)(ws + (1 << 20) + (256 << 10) + (8 << 20)); // 8 MB

    detect_mask_kernel<<<1, 256, 0, stream>>>((const unsigned int*)child_mask_raw, flag);
    mask_bits_kernel<<<(LL * NN + 255) / 256, 256, 0, stream>>>(
        child_mask_raw, flag, mbits);
    pack_weights_kernel<<<25, 256, 0, stream>>>(Wg, Wih, Whh, bih, bhh,
                                                WgHi, WgLo, WdHi, WdLo, bias);

    // Levels reversed; level L-1 (s=0) has all-false masks -> Hp never read,
    // so gemm_wg is launched only for s>=1.
    const float* hp = nullptr;
    for (int s = 0; s < LL; ++s) {
        const int l = LL - 1 - s;
        float* ho = (s & 1) ? out : hbuf;
        if (s > 0)
            gemm_wg_kernel<<<NN / 64, 256, 0, stream>>>(hp, WgHi, WgLo, Hp);
        level_kernel<<<NN / BN, 256, 0, stream>>>(
            node_features + (size_t)l * NN * FF,
            child_idx     + (size_t)l * NN * CC,
            mbits         + (size_t)l * NN,
            Hp,
            A_c           + (size_t)l * NN * CC * CC,
            WdHi, WdLo, bias,
            ho);
        hp = ho;
    }
}

// Round 6
// 154.208 us; speedup vs baseline: 6.1883x; 1.3257x over previous
//
#include <hip/hip_runtime.h>
#include <cfloat>

// Problem constants: L=6, N=16384, C=8, F=128, H=128
#define LL 6
#define NN 16384
#define CC 8
#define FF 128
#define HH 128
#define BN 16   // nodes per block (level kernel)

typedef __bf16 bf16x8 __attribute__((ext_vector_type(8)));
typedef __attribute__((ext_vector_type(4))) float f32x4;

static __device__ inline unsigned short f2bfbits(float f) {
    return __builtin_bit_cast(unsigned short, (__bf16)f);
}
static __device__ inline float bfbits2f(unsigned short b) {
    return (float)__builtin_bit_cast(__bf16, b);
}

// ---------------------------------------------------------------------------
// child_mask dtype detection (bool may arrive as u8 or int32). int32 0/1 LE
// values have all bytes at offset %4!=0 zero. Byte-layout random 0/1 bytes
// violate that w.p. 7/8 per dword. Parallel 2048 B scan. flag=1 -> int32.
// ---------------------------------------------------------------------------
__global__ void detect_mask_kernel(const unsigned int* __restrict__ raw,
                                   int* __restrict__ flag) {
    __shared__ int any;
    if (threadIdx.x == 0) any = 0;
    __syncthreads();
    const unsigned int a = raw[threadIdx.x * 2 + 0];
    const unsigned int b = raw[threadIdx.x * 2 + 1];
    if (((a | b) & 0xFFFFFF00u) != 0) atomicOr(&any, 1);
    __syncthreads();
    if (threadIdx.x == 0) *flag = any ? 0 : 1;
}

// Per-node 8-bit child mask, one thread per node.
__global__ void mask_bits_kernel(const unsigned char* __restrict__ raw,
                                 const int* __restrict__ flag,
                                 unsigned char* __restrict__ mbits) {
    const int n = blockIdx.x * blockDim.x + threadIdx.x;
    if (n >= LL * NN) return;
    const int f = *flag;
    unsigned char b;
    if (f) {
        const uint4 v0 = *(const uint4*)(raw + (size_t)n * 32);
        const uint4 v1 = *(const uint4*)(raw + (size_t)n * 32 + 16);
        b = (v0.x ? 1 : 0) | (v0.y ? 2 : 0) | (v0.z ? 4 : 0) | (v0.w ? 8 : 0)
          | (v1.x ? 16 : 0) | (v1.y ? 32 : 0) | (v1.z ? 64 : 0) | (v1.w ? 128 : 0);
    } else {
        const unsigned a = *(const unsigned*)(raw + (size_t)n * 8);
        const unsigned c = *(const unsigned*)(raw + (size_t)n * 8 + 4);
        b = ((a & 0xFFu) ? 1 : 0) | ((a & 0xFF00u) ? 2 : 0)
          | ((a & 0xFF0000u) ? 4 : 0) | ((a >> 24) ? 8 : 0)
          | ((c & 0xFFu) ? 16 : 0) | ((c & 0xFF00u) ? 32 : 0)
          | ((c & 0xFF0000u) ? 64 : 0) | ((c >> 24) ? 128 : 0);
    }
    mbits[n] = b;
}

// ---------------------------------------------------------------------------
// One-time weight packing into MFMA B-fragment order, split hi/lo bf16.
// B-frag (16x16x32): lane l supplies B[k][n], n = l&15, k = 8*(l>>4)+i.
// WgHi/WgLo : [nt(8)][kt(4)][lane(64)][i(8)] of Wg
// WdHi/WdLo : [nt(8)][kt(8)][lane(64)][i(8)] of [Wih;Whh]
// ---------------------------------------------------------------------------
__global__ void pack_weights_kernel(const float* __restrict__ Wg,
                                    const float* __restrict__ Wih,
                                    const float* __restrict__ Whh,
                                    const float* __restrict__ bih,
                                    const float* __restrict__ bhh,
                                    unsigned short* __restrict__ WgHi,
                                    unsigned short* __restrict__ WgLo,
                                    unsigned short* __restrict__ WdHi,
                                    unsigned short* __restrict__ WdLo,
                                    float* __restrict__ bias) {
    const int t = blockIdx.x * 256 + threadIdx.x;
    if (t < 2048) {                      // Wg: (nt*4+kt)*64+lane == t
        const int l = t & 63;
        const int nt = t >> 8;
        const int kt = (t >> 6) & 3;
        const int n = nt * 16 + (l & 15);
        const int kb = kt * 32 + (l >> 4) * 8;
        #pragma unroll
        for (int i = 0; i < 8; ++i) {
            const float v = Wg[(kb + i) * HH + n];
            const unsigned short hb = f2bfbits(v);
            WgHi[t * 8 + i] = hb;
            WgLo[t * 8 + i] = f2bfbits(v - bfbits2f(hb));
        }
    } else if (t < 6144) {               // Wd: u = (nt*8+kt)*64+lane
        const int u = t - 2048;
        const int l = u & 63;
        const int nt = u >> 9;
        const int kt = (u >> 6) & 7;
        const int n = nt * 16 + (l & 15);
        const int kb = (kt & 3) * 32 + (l >> 4) * 8;
        const float* W = (kt < 4) ? Wih : Whh;
        #pragma unroll
        for (int i = 0; i < 8; ++i) {
            const float v = W[(kb + i) * HH + n];
            const unsigned short hb = f2bfbits(v);
            WdHi[u * 8 + i] = hb;
            WdLo[u * 8 + i] = f2bfbits(v - bfbits2f(hb));
        }
    } else if (t < 6272) {
        const int n = t - 6144;
        bias[n] = bih[n] + bhh[n];
    }
}

// byte-offset swizzle for 256B-stride rows (breaks bank conflicts; residual
// 2-way aliasing is free per m136)
#define SWZ(row, byte) ((unsigned)(((row) * 256 + (byte)) ^ (((row) & 7) << 4)))

// ---------------------------------------------------------------------------
// One level, fully fused. Block: 256 threads = 4 waves; BN=16 nodes.
// Phase A: gather Hp_in rows of masked children, 8x8 mix in fp32
// (A_c @ (ch@Wg) == (A_c@ch)@Wg), relu + masked maxpool -> pooled (LDS).
// GEMM-D: [x|pooled] @ [Wih;Whh] split-bf16 -> h_new = tanh(.) -> h_out.
// Epilogue (unless last level): Hp_out = h_new @ Wg split-bf16 via LDS
// transpose (replaces the former standalone gemm_wg kernel). Hp_in/Hp_out
// are distinct buffers (ping-pong) -- same-kernel blocks race otherwise.
// ---------------------------------------------------------------------------
__global__ __launch_bounds__(256) void level_kernel(
    const float* __restrict__ x_l,            // [N][F]
    const int* __restrict__ cidx_l,           // [N][C]
    const unsigned char* __restrict__ mbits_l,// [N] child bitmask
    const float* __restrict__ Hp_in,          // [N][H] = h_prev @ Wg
    const float* __restrict__ a_l,            // [N][C][C]
    const unsigned short* __restrict__ WgHi,
    const unsigned short* __restrict__ WgLo,
    const unsigned short* __restrict__ WdHi,
    const unsigned short* __restrict__ WdLo,
    const float* __restrict__ bias,
    float* __restrict__ h_out,                // [N][H]
    float* __restrict__ Hp_out)               // [N][H] or nullptr (last level)
{
    __shared__ __align__(16) unsigned char pH[BN * 256];   // 4 KB pooled hi
    __shared__ __align__(16) unsigned char pL[BN * 256];   // 4 KB pooled lo
    __shared__ __align__(16) unsigned char hH[BN * 256];   // 4 KB h hi (epi)
    __shared__ __align__(16) unsigned char hL[BN * 256];   // 4 KB h lo (epi)
    __shared__ float a_lds[BN][CC][CC];                    // 4 KB
    __shared__ int   cidx_lds[BN][CC];
    __shared__ __align__(16) unsigned char maskbyte[BN];

    const int tid = threadIdx.x;
    const int lane = tid & 63;
    const int w = tid >> 6;
    const int lrow = lane & 15, lgrp = lane >> 4;
    const long nbase = (long)blockIdx.x * BN;

    // --- stage per-node small data ---
    ((float4*)a_lds)[tid] = ((const float4*)(a_l + nbase * CC * CC))[tid];
    if (tid < 32)
        ((uint4*)cidx_lds)[tid] = ((const uint4*)(cidx_l + nbase * CC))[tid];
    if (tid < BN) maskbyte[tid] = mbits_l[nbase + tid];

    // --- early x loads (raw fp32, consumed in GEMM-D) ---
    float4 xr[8];
    #pragma unroll
    for (int kt = 0; kt < 4; ++kt) {
        const float* src = &x_l[(nbase + lrow) * FF + kt * 32 + lgrp * 8];
        xr[kt * 2 + 0] = *(const float4*)src;
        xr[kt * 2 + 1] = *(const float4*)(src + 4);
    }
    __syncthreads();

    const uint4 mball = *(const uint4*)maskbyte;
    const int any = (mball.x | mball.y | mball.z | mball.w) != 0;  // block-uniform

    // --- Phase A: gather Hp + 8x8 mix + relu + masked maxpool -> pooled ---
    if (any) {
        for (int nl = 0; nl < 4; ++nl) {
            const int node = w * 4 + nl;
            const int mb = maskbyte[node];           // wave-uniform
            float m0 = 0.f, m1 = 0.f;
            if (mb) {
                float c0[CC], c1[CC];
                #pragma unroll
                for (int c = 0; c < CC; ++c) { c0[c] = 0.f; c1[c] = 0.f; }
                #pragma unroll
                for (int c = 0; c < CC; ++c) {
                    if (mb & (1 << c)) {
                        const float2 v = *(const float2*)&Hp_in[(size_t)cidx_lds[node][c] * HH + 2 * lane];
                        c0[c] = v.x; c1[c] = v.y;
                    }
                }
                float mm0 = -FLT_MAX, mm1 = -FLT_MAX;
                #pragma unroll
                for (int c = 0; c < CC; ++c) {
                    if (mb & (1 << c)) {
                        float s0 = 0.f, s1 = 0.f;
                        #pragma unroll
                        for (int d = 0; d < CC; ++d) {
                            const float av = a_lds[node][c][d];
                            s0 += av * c0[d]; s1 += av * c1[d];
                        }
                        mm0 = fmaxf(mm0, fmaxf(s0, 0.f));
                        mm1 = fmaxf(mm1, fmaxf(s1, 0.f));
                    }
                }
                m0 = mm0; m1 = mm1;
            }
            const unsigned short h0 = f2bfbits(m0);
            const unsigned short h1 = f2bfbits(m1);
            const unsigned short l0 = f2bfbits(m0 - bfbits2f(h0));
            const unsigned short l1 = f2bfbits(m1 - bfbits2f(h1));
            const unsigned off = SWZ(node, lane * 4);   // cols 2*lane, 2*lane+1
            *(unsigned*)&pH[off] = (unsigned)h0 | ((unsigned)h1 << 16);
            *(unsigned*)&pL[off] = (unsigned)l0 | ((unsigned)l1 << 16);
        }
        __syncthreads();
    }

    // --- GEMM-D: h = tanh([x|pooled] @ [Wih;Whh] + b), split-bf16 ---
    bf16x8 ah[8], al[8];
    #pragma unroll
    for (int kt = 0; kt < 4; ++kt) {   // x part from preloaded registers
        const float4 v0 = xr[kt * 2 + 0];
        const float4 v1 = xr[kt * 2 + 1];
        const float vv[8] = {v0.x, v0.y, v0.z, v0.w, v1.x, v1.y, v1.z, v1.w};
        bf16x8 hfr, lfr;
        #pragma unroll
        for (int i = 0; i < 8; ++i) {
            const __bf16 hb = (__bf16)vv[i];
            hfr[i] = hb;
            lfr[i] = (__bf16)(vv[i] - (float)hb);
        }
        ah[kt] = hfr; al[kt] = lfr;
    }
    if (any) {
        #pragma unroll
        for (int kt = 4; kt < 8; ++kt) {   // pooled part from LDS
            const unsigned off = SWZ(lrow, (kt - 4) * 64 + lgrp * 16);
            ah[kt] = *(const bf16x8*)&pH[off];
            al[kt] = *(const bf16x8*)&pL[off];
        }
    }
    float hv[2][4];
    #pragma unroll
    for (int nn = 0; nn < 2; ++nn) {
        const int nt = w * 2 + nn;
        f32x4 acc = {0.f, 0.f, 0.f, 0.f};
        #pragma unroll
        for (int kt = 0; kt < 4; ++kt) {
            const bf16x8 bh = *(const bf16x8*)&WdHi[((nt * 8 + kt) * 64 + lane) * 8];
            const bf16x8 bl = *(const bf16x8*)&WdLo[((nt * 8 + kt) * 64 + lane) * 8];
            acc = __builtin_amdgcn_mfma_f32_16x16x32_bf16(ah[kt], bh, acc, 0, 0, 0);
            acc = __builtin_amdgcn_mfma_f32_16x16x32_bf16(ah[kt], bl, acc, 0, 0, 0);
            acc = __builtin_amdgcn_mfma_f32_16x16x32_bf16(al[kt], bh, acc, 0, 0, 0);
        }
        if (any) {
            #pragma unroll
            for (int kt = 4; kt < 8; ++kt) {
                const bf16x8 bh = *(const bf16x8*)&WdHi[((nt * 8 + kt) * 64 + lane) * 8];
                const bf16x8 bl = *(const bf16x8*)&WdLo[((nt * 8 + kt) * 64 + lane) * 8];
                acc = __builtin_amdgcn_mfma_f32_16x16x32_bf16(ah[kt], bh, acc, 0, 0, 0);
                acc = __builtin_amdgcn_mfma_f32_16x16x32_bf16(ah[kt], bl, acc, 0, 0, 0);
                acc = __builtin_amdgcn_mfma_f32_16x16x32_bf16(al[kt], bh, acc, 0, 0, 0);
            }
        }
        const float b = bias[nt * 16 + lrow];
        #pragma unroll
        for (int r = 0; r < 4; ++r) {
            const float h = tanhf(acc[r] + b);
            hv[nn][r] = h;
            h_out[(nbase + lgrp * 4 + r) * HH + nt * 16 + lrow] = h;
        }
    }

    // --- Epilogue: Hp_out = h_new @ Wg (split-bf16) via LDS transpose ---
    if (Hp_out != nullptr) {
        #pragma unroll
        for (int nn = 0; nn < 2; ++nn) {
            #pragma unroll
            for (int r = 0; r < 4; ++r) {
                const int row = lgrp * 4 + r;               // node in block
                const int col = (w * 2 + nn) * 16 + lrow;   // h column
                const unsigned short hb = f2bfbits(hv[nn][r]);
                const unsigned short lb = f2bfbits(hv[nn][r] - bfbits2f(hb));
                const unsigned off = SWZ(row, col * 2);
                *(unsigned short*)&hH[off] = hb;
                *(unsigned short*)&hL[off] = lb;
            }
        }
        __syncthreads();
        bf16x8 aHh[4], aLh[4];
        #pragma unroll
        for (int kt = 0; kt < 4; ++kt) {
            const unsigned off = SWZ(lrow, kt * 64 + lgrp * 16);
            aHh[kt] = *(const bf16x8*)&hH[off];
            aLh[kt] = *(const bf16x8*)&hL[off];
        }
        #pragma unroll
        for (int nn = 0; nn < 2; ++nn) {
            const int nt = w * 2 + nn;
            f32x4 acc = {0.f, 0.f, 0.f, 0.f};
            #pragma unroll
            for (int kt = 0; kt < 4; ++kt) {
                const bf16x8 bh = *(const bf16x8*)&WgHi[((nt * 4 + kt) * 64 + lane) * 8];
                const bf16x8 bl = *(const bf16x8*)&WgLo[((nt * 4 + kt) * 64 + lane) * 8];
                acc = __builtin_amdgcn_mfma_f32_16x16x32_bf16(aHh[kt], bh, acc, 0, 0, 0);
                acc = __builtin_amdgcn_mfma_f32_16x16x32_bf16(aHh[kt], bl, acc, 0, 0, 0);
                acc = __builtin_amdgcn_mfma_f32_16x16x32_bf16(aLh[kt], bh, acc, 0, 0, 0);
            }
            #pragma unroll
            for (int r = 0; r < 4; ++r)
                Hp_out[(nbase + lgrp * 4 + r) * HH + nt * 16 + lrow] = acc[r];
        }
    }
}

extern "C" void kernel_launch(void* const* d_in, const int* in_sizes, int n_in,
                              void* d_out, int out_size, void* d_ws, size_t ws_size,
                              hipStream_t stream) {
    const float* node_features = (const float*)d_in[0];
    const int*   child_idx     = (const int*)d_in[1];
    const unsigned char* child_mask_raw = (const unsigned char*)d_in[2];
    const float* A_c  = (const float*)d_in[3];
    const float* Wg   = (const float*)d_in[4];
    const float* Wih  = (const float*)d_in[5];
    const float* Whh  = (const float*)d_in[6];
    const float* bih  = (const float*)d_in[7];
    const float* bhh  = (const float*)d_in[8];
    float* out = (float*)d_out;

    char* ws = (char*)d_ws;
    int* flag = (int*)ws;
    unsigned char* mbits = (unsigned char*)(ws + 256);                      // 96 KB
    unsigned short* WgHi = (unsigned short*)(ws + (1 << 20));               // 32 KB
    unsigned short* WgLo = (unsigned short*)(ws + (1 << 20) + (32 << 10));  // 32 KB
    unsigned short* WdHi = (unsigned short*)(ws + (1 << 20) + (64 << 10));  // 64 KB
    unsigned short* WdLo = (unsigned short*)(ws + (1 << 20) + (128 << 10)); // 64 KB
    float* bias          = (float*)(ws + (1 << 20) + (192 << 10));
    float* hbuf          = (float*)(ws + (1 << 20) + (256 << 10));              // 8 MB
    float* HpA           = (float*)(ws + (1 << 20) + (256 << 10) + (8 << 20));  // 8 MB
    float* HpB           = (float*)(ws + (1 << 20) + (256 << 10) + (16 << 20)); // 8 MB

    detect_mask_kernel<<<1, 256, 0, stream>>>((const unsigned int*)child_mask_raw, flag);
    mask_bits_kernel<<<(LL * NN + 255) / 256, 256, 0, stream>>>(
        child_mask_raw, flag, mbits);
    pack_weights_kernel<<<25, 256, 0, stream>>>(Wg, Wih, Whh, bih, bhh,
                                                WgHi, WgLo, WdHi, WdLo, bias);

    // Levels reversed; s=0 (level L-1) has all-false masks -> Hp_in unread
    // (any==0 in every block). Epilogue of level s writes Hp for level s+1
    // into the OTHER Hp buffer (ping-pong; same-kernel blocks would race on
    // a single buffer). Last level skips the epilogue.
    for (int s = 0; s < LL; ++s) {
        const int l = LL - 1 - s;
        float* ho = (s & 1) ? out : hbuf;
        float* hp_in  = (s & 1) ? HpB : HpA;
        float* hp_out = (s & 1) ? HpA : HpB;
        level_kernel<<<NN / BN, 256, 0, stream>>>(
            node_features + (size_t)l * NN * FF,
            child_idx     + (size_t)l * NN * CC,
            mbits         + (size_t)l * NN,
            hp_in,
            A_c           + (size_t)l * NN * CC * CC,
            WgHi, WgLo, WdHi, WdLo, bias,
            ho,
            (s == LL - 1) ? nullptr : hp_out);
    }
}